// Round 1
// baseline (321.286 us; speedup 1.0000x reference)
//
#include <hip/hip_runtime.h>

// Colorcal: out[b,c,h,w] = image[b,c,h,w] * weight[cam[b],c] + bias[cam[b],c]
// image: [16,3,1024,1024] fp32.  Pure memory-bound elementwise op.
// One float4 per thread; plane (b,c) = i>>18 since each plane = 2^18 float4s.

#define PLANE_F4_SHIFT 18  // 1024*1024/4 = 262144 = 2^18 float4 per (b,c) plane

__global__ __launch_bounds__(256) void colorcal_kernel(
    const float4* __restrict__ img,
    const int*    __restrict__ cam_idx,
    const float*  __restrict__ weight,
    const float*  __restrict__ bias,
    float4*       __restrict__ out)
{
    int i = blockIdx.x * blockDim.x + threadIdx.x;   // < 12,582,912 — fits int
    int plane = i >> PLANE_F4_SHIFT;                 // 0..47  (b*3 + c)
    int b = plane / 3;
    int c = plane - b * 3;
    int cam = cam_idx[b];
    float s = weight[cam * 3 + c];
    float t = bias[cam * 3 + c];
    float4 v = img[i];
    v.x = fmaf(v.x, s, t);
    v.y = fmaf(v.y, s, t);
    v.z = fmaf(v.z, s, t);
    v.w = fmaf(v.w, s, t);
    out[i] = v;
}

extern "C" void kernel_launch(void* const* d_in, const int* in_sizes, int n_in,
                              void* d_out, int out_size, void* d_ws, size_t ws_size,
                              hipStream_t stream)
{
    const float4* img     = (const float4*)d_in[0];
    const int*    cam_idx = (const int*)d_in[1];
    const float*  weight  = (const float*)d_in[2];
    const float*  bias    = (const float*)d_in[3];
    float4*       out     = (float4*)d_out;

    const int n_f4 = out_size / 4;                   // 12,582,912
    const int block = 256;
    const int grid = (n_f4 + block - 1) / block;     // 49,152 blocks
    colorcal_kernel<<<grid, block, 0, stream>>>(img, cam_idx, weight, bias, out);
}

// Round 3
// 318.711 us; speedup vs baseline: 1.0081x; 1.0081x over previous
//
#include <hip/hip_runtime.h>

// Colorcal: out[b,c,h,w] = image[b,c,h,w] * weight[cam[b],c] + bias[cam[b],c]
// image: [16,3,1024,1024] fp32. Memory-bound: 402 MB mandatory traffic.
//
// vs R2: native ext_vector_type float4 (HIP_vector_type is rejected by the
// nontemporal builtins). Plane index from blockIdx (wave-uniform) keeps the
// cam/weight/bias gather chain in s_loads; nt hints keep the 402 MB stream
// out of L2/L3.
//
// Each (b,c) plane = 1024*1024 floats = 2^18 float4 = 1024 blocks of 256.

typedef float f4 __attribute__((ext_vector_type(4)));

__global__ __launch_bounds__(256) void colorcal_kernel(
    const f4*    __restrict__ img,
    const int*   __restrict__ cam_idx,
    const float* __restrict__ weight,
    const float* __restrict__ bias,
    f4*          __restrict__ out)
{
    // Wave-uniform scalar arithmetic (blockIdx lives in SGPRs):
    const int plane = blockIdx.x >> 10;       // 0..47  (b*3 + c)
    const int b     = plane / 3;
    const int c     = plane - b * 3;
    const int cam   = cam_idx[b];             // s_load (block-uniform)
    const float s   = weight[cam * 3 + c];    // s_load
    const float t   = bias[cam * 3 + c];      // s_load

    const int i = blockIdx.x * 256 + threadIdx.x;   // float4 index, < 12.6M

    f4 v = __builtin_nontemporal_load(&img[i]);
    v.x = fmaf(v.x, s, t);
    v.y = fmaf(v.y, s, t);
    v.z = fmaf(v.z, s, t);
    v.w = fmaf(v.w, s, t);
    __builtin_nontemporal_store(v, &out[i]);
}

extern "C" void kernel_launch(void* const* d_in, const int* in_sizes, int n_in,
                              void* d_out, int out_size, void* d_ws, size_t ws_size,
                              hipStream_t stream)
{
    const f4*    img     = (const f4*)d_in[0];
    const int*   cam_idx = (const int*)d_in[1];
    const float* weight  = (const float*)d_in[2];
    const float* bias    = (const float*)d_in[3];
    f4*          out     = (f4*)d_out;

    const int n_f4  = out_size / 4;                  // 12,582,912
    const int block = 256;
    const int grid  = n_f4 / block;                  // 49,152 blocks (exact)
    colorcal_kernel<<<grid, block, 0, stream>>>(img, cam_idx, weight, bias, out);
}